// Round 1
// baseline (486.441 us; speedup 1.0000x reference)
//
#include <hip/hip_runtime.h>
#include <hip/hip_bf16.h>
#include <math.h>

// Problem constants
#define H_      8
#define E_      256
#define V_      1024
#define MLEN    64
#define B_      512
#define QKV_C   6144   // 3*E*H
#define HSTR    768    // 3*E

// ---------------------------------------------------------------------------
// Positional encoding: pe[m][2k] = sin(m*freq[k]), pe[m][2k+1] = cos(m*freq[k])
// freq[k] = 10000^(-k/128) (f32 cumprod in ref; double pow here, diff ~1e-6)
// ---------------------------------------------------------------------------
__global__ void pos_kernel(float* __restrict__ pe) {
  const int m = blockIdx.x;     // 0..63
  const int k = threadIdx.x;    // 0..127
  double f = pow(10000.0, -(double)k / 128.0);
  float ph = (float)m * (float)f;
  pe[m * E_ + 2 * k]     = sinf(ph);
  pe[m * E_ + 2 * k + 1] = cosf(ph);
}

// ---------------------------------------------------------------------------
// Generic strided/batched GEMM: C[z][m][n] = sum_k A[z][m][k] * B[z][n][k]
// A: lda row stride, B: ldb, C: ldc. Batch strides sA/sB/sC, grid.z batches.
// BM=BN=64, BK=16, 256 threads, 4x4 per-thread tile. M%64==0, N%64==0, K%16==0.
// ---------------------------------------------------------------------------
template<bool BIAS>
__global__ __launch_bounds__(256) void gemm_abt(
    const float* __restrict__ A, const float* __restrict__ B,
    const float* __restrict__ bias, float* __restrict__ C,
    int M, int N, int K, int lda, int ldb, int ldc,
    long sA, long sB, long sC)
{
  __shared__ float As[16][65];
  __shared__ float Bs[16][65];
  const int z = blockIdx.z;
  A += (size_t)z * sA;  B += (size_t)z * sB;  C += (size_t)z * sC;
  const int m0 = blockIdx.y * 64, n0 = blockIdx.x * 64;
  const int tid = threadIdx.x;
  const int tr = tid >> 4, tc = tid & 15;
  const int lm = tid >> 2;            // 0..63
  const int lk = (tid & 3) << 2;      // 0,4,8,12
  float acc[4][4] = {};
  for (int k0 = 0; k0 < K; k0 += 16) {
    const float4 av = *(const float4*)(A + (size_t)(m0 + lm) * lda + k0 + lk);
    const float4 bv = *(const float4*)(B + (size_t)(n0 + lm) * ldb + k0 + lk);
    __syncthreads();
    As[lk + 0][lm] = av.x; As[lk + 1][lm] = av.y; As[lk + 2][lm] = av.z; As[lk + 3][lm] = av.w;
    Bs[lk + 0][lm] = bv.x; Bs[lk + 1][lm] = bv.y; Bs[lk + 2][lm] = bv.z; Bs[lk + 3][lm] = bv.w;
    __syncthreads();
    #pragma unroll
    for (int k = 0; k < 16; ++k) {
      float a[4], b[4];
      #pragma unroll
      for (int d = 0; d < 4; ++d) { a[d] = As[k][tr * 4 + d]; b[d] = Bs[k][tc * 4 + d]; }
      #pragma unroll
      for (int i = 0; i < 4; ++i)
        #pragma unroll
        for (int j = 0; j < 4; ++j) acc[i][j] += a[i] * b[j];
    }
  }
  #pragma unroll
  for (int i = 0; i < 4; ++i) {
    #pragma unroll
    for (int j = 0; j < 4; ++j) {
      const int n = n0 + tc * 4 + j;
      float v = acc[i][j];
      if (BIAS) v += bias[n];
      C[(size_t)(m0 + tr * 4 + i) * ldc + n] = v;
    }
  }
}

// ---------------------------------------------------------------------------
// Attention per (b,h): sim = (cq[c_i]·(ck[c_j]+pk[j]) + t1[h,c_i,j] + pqk[h,i,j])/16
// mask c_j==PAD -> -1e9; softmax over j; pooled[j]=sum_i notm[i]*attn[i][j]/nw;
// out[b,h,e] = sum_j pooled[j]*(cv[c_j][e]+pv[j][e])
// ---------------------------------------------------------------------------
__global__ __launch_bounds__(256) void attn_kernel(
    const int* __restrict__ cc, const float* __restrict__ cqkv,
    const float* __restrict__ pqkv, const float* __restrict__ t1,
    const float* __restrict__ pqk, float* __restrict__ outp)
{
  __shared__ float Qs[64][65];
  __shared__ float Ks[64][65];
  __shared__ float sims[64][65];
  __shared__ int   cs[MLEN];
  __shared__ float notm[MLEN];
  __shared__ float pooled[MLEN];
  __shared__ float nwords;
  const int b = blockIdx.x, h = blockIdx.y;
  const int tid = threadIdx.x;
  const int hq = h * HSTR;

  if (tid < 64) {
    const int cv_ = cc[b * 64 + tid];
    cs[tid] = cv_;
    notm[tid] = (cv_ != 0) ? 1.f : 0.f;
    unsigned long long bm = __ballot(cv_ != 0);
    if (tid == 0) nwords = (float)__popcll(bm);
  }
  __syncthreads();

  const int tr = tid >> 4, tc = tid & 15;
  const int le  = tid & 63;    // col within 64-chunk
  const int lr0 = tid >> 6;    // 0..3
  float acc[4][4] = {};

  for (int ec = 0; ec < 4; ++ec) {
    __syncthreads();
    #pragma unroll
    for (int it = 0; it < 16; ++it) {
      const int r = lr0 + it * 4;
      const int ci = cs[r];
      const int off = hq + ec * 64 + le;
      Qs[r][le] = cqkv[(size_t)ci * QKV_C + off];
      Ks[r][le] = cqkv[(size_t)ci * QKV_C + off + 256] + pqkv[(size_t)r * QKV_C + off + 256];
    }
    __syncthreads();
    #pragma unroll 8
    for (int e = 0; e < 64; ++e) {
      float q[4], k4[4];
      #pragma unroll
      for (int d = 0; d < 4; ++d) { q[d] = Qs[tr * 4 + d][e]; k4[d] = Ks[tc * 4 + d][e]; }
      #pragma unroll
      for (int i = 0; i < 4; ++i)
        #pragma unroll
        for (int j = 0; j < 4; ++j) acc[i][j] += q[i] * k4[j];
    }
  }

  // stage table rows into Qs (t1 gathered by c_i) and Ks (pqk by i)
  __syncthreads();
  #pragma unroll
  for (int it = 0; it < 16; ++it) {
    const int r = lr0 + it * 4;
    Qs[r][le] = t1[(size_t)h * 65536 + (size_t)cs[r] * 64 + le];
    Ks[r][le] = pqk[h * 4096 + r * 64 + le];
  }
  __syncthreads();

  const float scale = 0.0625f;  // 1/sqrt(256)
  #pragma unroll
  for (int i = 0; i < 4; ++i) {
    #pragma unroll
    for (int j = 0; j < 4; ++j) {
      const int ii = tr * 4 + i, jj = tc * 4 + j;
      float s = (acc[i][j] + Qs[ii][jj] + Ks[ii][jj]) * scale;
      if (cs[jj] == 0) s = -1e9f;
      sims[ii][jj] = s;
    }
  }
  __syncthreads();

  // softmax rows: 4 lanes per row
  const int row = tid >> 2, part = tid & 3;
  float m = -3e38f;
  #pragma unroll
  for (int j = 0; j < 16; ++j) m = fmaxf(m, sims[row][part * 16 + j]);
  m = fmaxf(m, __shfl_xor(m, 1));
  m = fmaxf(m, __shfl_xor(m, 2));
  float ssum = 0.f;
  #pragma unroll
  for (int j = 0; j < 16; ++j) {
    const float e = __expf(sims[row][part * 16 + j] - m);
    sims[row][part * 16 + j] = e;
    ssum += e;
  }
  ssum += __shfl_xor(ssum, 1);
  ssum += __shfl_xor(ssum, 2);
  const float w = notm[row] / ssum;
  #pragma unroll
  for (int j = 0; j < 16; ++j) sims[row][part * 16 + j] *= w;
  __syncthreads();

  if (tid < 64) {
    float p = 0.f;
    for (int i = 0; i < 64; ++i) p += sims[i][tid];
    pooled[tid] = p / nwords;
  }
  __syncthreads();

  // out: thread owns e = tid
  float o = 0.f;
  for (int j = 0; j < 64; ++j) {
    const int cj = cs[j];
    const float vv = cqkv[(size_t)cj * QKV_C + hq + 512 + tid]
                   + pqkv[(size_t)j  * QKV_C + hq + 512 + tid];
    o += pooled[j] * vv;
  }
  outp[(size_t)b * 2048 + h * 256 + tid] = o;
}

// ---------------------------------------------------------------------------
// LayerNorm chain: y1=LN(x,eps1e-5); y2=LN(y1,eps1e-6)+y1; out=LN(y2,eps1e-5)
// one block per row of 256
// ---------------------------------------------------------------------------
__global__ __launch_bounds__(256) void ln_chain(
    const float* __restrict__ x,
    const float* __restrict__ g1, const float* __restrict__ b1,
    const float* __restrict__ g2, const float* __restrict__ b2,
    const float* __restrict__ g3, const float* __restrict__ b3,
    float* __restrict__ out)
{
  __shared__ float red[4];
  const int b = blockIdx.x, t = threadIdx.x;
  float v = x[(size_t)b * E_ + t];

  auto bsum = [&](float val) -> float {
    #pragma unroll
    for (int o = 32; o; o >>= 1) val += __shfl_down(val, o);
    __syncthreads();
    if ((t & 63) == 0) red[t >> 6] = val;
    __syncthreads();
    return red[0] + red[1] + red[2] + red[3];
  };

  float mean = bsum(v) * (1.f / 256.f);
  float d = v - mean;
  float var = bsum(d * d) * (1.f / 256.f);
  const float y1 = d * rsqrtf(var + 1e-5f) * g1[t] + b1[t];

  mean = bsum(y1) * (1.f / 256.f);
  d = y1 - mean;
  var = bsum(d * d) * (1.f / 256.f);
  const float y2 = d * rsqrtf(var + 1e-6f) * g2[t] + b2[t] + y1;

  mean = bsum(y2) * (1.f / 256.f);
  d = y2 - mean;
  var = bsum(d * d) * (1.f / 256.f);
  out[(size_t)b * E_ + t] = d * rsqrtf(var + 1e-5f) * g3[t] + b3[t];
}

// ---------------------------------------------------------------------------
extern "C" void kernel_launch(void* const* d_in, const int* in_sizes, int n_in,
                              void* d_out, int out_size, void* d_ws, size_t ws_size,
                              hipStream_t stream) {
  (void)in_sizes; (void)n_in; (void)out_size; (void)ws_size;
  const int*   cc    = (const int*)  d_in[0];   // (512,64)
  const float* emb_w = (const float*)d_in[1];   // (1024,256)
  const float* qkv_w = (const float*)d_in[2];   // (6144,256)
  const float* fc_w  = (const float*)d_in[3];   // (256,2048)
  const float* fc_b  = (const float*)d_in[4];
  const float* sg    = (const float*)d_in[5];
  const float* sb    = (const float*)d_in[6];
  const float* fg    = (const float*)d_in[7];
  const float* fb    = (const float*)d_in[8];
  const float* bg    = (const float*)d_in[9];
  const float* bbv   = (const float*)d_in[10];
  // d_in[11] = max_len (always 64 for this harness)
  float* out = (float*)d_out;

  float* pe   = (float*)d_ws;                         // 64*256
  float* cqkv = pe   + (size_t)64 * 256;              // 1024*6144
  float* pqkv = cqkv + (size_t)1024 * 6144;           // 64*6144
  float* t1   = pqkv + (size_t)64 * 6144;             // 8*1024*64
  float* pqk  = t1   + (size_t)8 * 1024 * 64;         // 8*64*64
  float* sdpa = pqk  + (size_t)8 * 64 * 64;           // 512*2048
  float* fco  = sdpa + (size_t)512 * 2048;            // 512*256

  pos_kernel<<<dim3(64), dim3(128), 0, stream>>>(pe);

  // cqkv = emb_w @ qkv_w^T   (1024 x 6144, K=256)
  gemm_abt<false><<<dim3(96, 16, 1), dim3(256), 0, stream>>>(
      emb_w, qkv_w, nullptr, cqkv, 1024, 6144, 256, 256, 256, 6144, 0, 0, 0);
  // pqkv = pe @ qkv_w^T      (64 x 6144, K=256)
  gemm_abt<false><<<dim3(96, 1, 1), dim3(256), 0, stream>>>(
      pe, qkv_w, nullptr, pqkv, 64, 6144, 256, 256, 256, 6144, 0, 0, 0);
  // t1[h] = ck_h @ pq_h^T    (1024 x 64, K=256), batched over h
  gemm_abt<false><<<dim3(1, 16, 8), dim3(256), 0, stream>>>(
      cqkv + 256, pqkv, nullptr, t1, 1024, 64, 256, QKV_C, QKV_C, 64,
      HSTR, HSTR, (long)1024 * 64);
  // pqk[h] = pq_h @ pk_h^T   (64 x 64, K=256), batched over h
  gemm_abt<false><<<dim3(1, 1, 8), dim3(256), 0, stream>>>(
      pqkv, pqkv + 256, nullptr, pqk, 64, 64, 256, QKV_C, QKV_C, 64,
      HSTR, HSTR, (long)64 * 64);

  attn_kernel<<<dim3(512, 8), dim3(256), 0, stream>>>(cc, cqkv, pqkv, t1, pqk, sdpa);

  // fco = sdpa @ fc_w^T + fc_b  (512 x 256, K=2048)
  gemm_abt<true><<<dim3(4, 8, 1), dim3(256), 0, stream>>>(
      sdpa, fc_w, fc_b, fco, 512, 256, 2048, 2048, 2048, 256, 0, 0, 0);

  ln_chain<<<dim3(512), dim3(256), 0, stream>>>(fco, sg, sb, fg, fb, bg, bbv, out);
}

// Round 2
// 197.839 us; speedup vs baseline: 2.4588x; 2.4588x over previous
//
#include <hip/hip_runtime.h>
#include <math.h>

typedef unsigned short u16;
typedef __attribute__((ext_vector_type(4))) float f32x4;
typedef __attribute__((ext_vector_type(8))) short s16x8;   // MFMA bf16 frag (8 bf16)
typedef __attribute__((ext_vector_type(4))) unsigned short u16x4;
typedef __attribute__((ext_vector_type(8))) unsigned short u16x8;

__device__ __forceinline__ u16 f2b(float f) {
  union { float f; unsigned u; } v; v.f = f;
  return (u16)((v.u + 0x7fffu + ((v.u >> 16) & 1u)) >> 16);
}
__device__ __forceinline__ float b2f(u16 b) {
  union { unsigned u; float f; } v; v.u = ((unsigned)b) << 16;
  return v.f;
}

// ---------------------------------------------------------------------------
// f32 -> bf16 cast (vectorized, n % 4 == 0)
// ---------------------------------------------------------------------------
__global__ __launch_bounds__(256) void cast_bf(const float* __restrict__ in,
                                               u16* __restrict__ out, int n4) {
  const int i = blockIdx.x * 256 + threadIdx.x;
  if (i < n4) {
    f32x4 v = *(const f32x4*)&in[i * 4];
    u16x4 o = { f2b(v[0]), f2b(v[1]), f2b(v[2]), f2b(v[3]) };
    *(u16x4*)&out[i * 4] = o;
  }
}

// ---------------------------------------------------------------------------
// Positional encoding directly in bf16
// ---------------------------------------------------------------------------
__global__ void pos_kernel(u16* __restrict__ pe) {
  const int m = blockIdx.x;     // 0..63
  const int k = threadIdx.x;    // 0..127
  double f = pow(10000.0, -(double)k / 128.0);
  float ph = (float)m * (float)f;
  pe[m * 256 + 2 * k]     = f2b(sinf(ph));
  pe[m * 256 + 2 * k + 1] = f2b(cosf(ph));
}

// ---------------------------------------------------------------------------
// bf16 MFMA GEMM: C[z][m][n] = sum_k A[z][m][k]*B[z][n][k]  (+C if ACCUM)(+bias)
// 64x64 tile, 256 threads = 4 waves, BK=64, XOR-swizzled LDS, 16x16x32 MFMA.
// M,N,K multiples of 64. lda/ldb/ldc/sA/sB/sC in elements.
// ---------------------------------------------------------------------------
template<bool CBF16, bool ACCUM, bool BIAS>
__global__ __launch_bounds__(256) void gemm_bf(
    const u16* __restrict__ A, int lda, long sA,
    const u16* __restrict__ B, int ldb, long sB,
    void* __restrict__ Cv, int ldc, long sC,
    const float* __restrict__ bias, int K)
{
  __shared__ __align__(16) u16 As[64 * 64];
  __shared__ __align__(16) u16 Bs[64 * 64];
  const int z = blockIdx.z;
  A += (long)z * sA;  B += (long)z * sB;
  const int m0 = blockIdx.y * 64, n0 = blockIdx.x * 64;
  const int tid = threadIdx.x;
  const int srow = tid >> 2, sq = tid & 3;
  const int w = tid >> 6, l = tid & 63, hi = l >> 4, lo = l & 15;
  f32x4 acc[4] = {};
  for (int k0 = 0; k0 < K; k0 += 64) {
    __syncthreads();
    #pragma unroll
    for (int p = 0; p < 2; ++p) {
      const int col = sq * 16 + p * 8;
      const int sidx = srow * 64 + (col ^ ((srow & 7) << 3));
      *(u16x8*)&As[sidx] = *(const u16x8*)&A[(long)(m0 + srow) * lda + k0 + col];
      *(u16x8*)&Bs[sidx] = *(const u16x8*)&B[(long)(n0 + srow) * ldb + k0 + col];
    }
    __syncthreads();
    #pragma unroll
    for (int kk = 0; kk < 2; ++kk) {
      const int arow = w * 16 + lo;
      s16x8 a = *(const s16x8*)&As[arow * 64 + ((hi * 8 + kk * 32) ^ ((arow & 7) << 3))];
      #pragma unroll
      for (int n = 0; n < 4; ++n) {
        const int brow = n * 16 + lo;
        s16x8 bfr = *(const s16x8*)&Bs[brow * 64 + ((hi * 8 + kk * 32) ^ ((brow & 7) << 3))];
        acc[n] = __builtin_amdgcn_mfma_f32_16x16x32_bf16(a, bfr, acc[n], 0, 0, 0);
      }
    }
  }
  const long zoff = (long)z * sC;
  #pragma unroll
  for (int n = 0; n < 4; ++n) {
    #pragma unroll
    for (int r = 0; r < 4; ++r) {
      const int row = m0 + w * 16 + hi * 4 + r;
      const int col = n0 + n * 16 + lo;
      if (CBF16) {
        ((u16*)Cv)[zoff + (long)row * ldc + col] = f2b(acc[n][r]);
      } else {
        float* C = (float*)Cv;
        float v = acc[n][r];
        if (ACCUM) v += C[zoff + (long)row * ldc + col];
        if (BIAS)  v += bias[col];
        C[zoff + (long)row * ldc + col] = v;
      }
    }
  }
}

// ---------------------------------------------------------------------------
// Attention per (b,h): MFMA QK^T on gathered bf16 rows + table adds +
// in-register softmax + pooled column-reduce + scalar PV.
// sim = (cq[c_i]·ck[c_j] + cpqk[h,c_i,j] + pqk[h,i,j]) / 16 ; mask c_j==0
// ---------------------------------------------------------------------------
__global__ __launch_bounds__(256) void attn_kernel(
    const int* __restrict__ cc, const u16* __restrict__ cqkv,
    const u16* __restrict__ pqkv, const float* __restrict__ cpqk,
    const float* __restrict__ pqk, u16* __restrict__ outp)
{
  __shared__ __align__(16) u16 Qs[64 * 256];
  __shared__ __align__(16) u16 Ks[64 * 256];
  __shared__ int   cs[64];
  __shared__ float notm[64];
  __shared__ float poolp[4][64];
  __shared__ float pooled[64];
  __shared__ float nwords;
  const int b = blockIdx.x, h = blockIdx.y;
  const int tid = threadIdx.x;
  const long hq = (long)h * 768;

  if (tid < 64) {
    const int c = cc[b * 64 + tid];
    cs[tid] = c;
    notm[tid] = c ? 1.f : 0.f;
    unsigned long long bm = __ballot(c != 0);
    if (tid == 0) nwords = (float)__popcll(bm);
  }
  __syncthreads();

  // stage Q (cq rows) and K (ck rows) as bf16, XOR-swizzled
  {
    const int srow = tid >> 2, sq = tid & 3;
    const long qbase = (long)cs[srow] * 6144 + hq;
    #pragma unroll
    for (int p = 0; p < 8; ++p) {
      const int col = sq * 64 + p * 8;
      const int sidx = srow * 256 + (col ^ ((srow & 7) << 3));
      *(u16x8*)&Qs[sidx] = *(const u16x8*)&cqkv[qbase + col];
      *(u16x8*)&Ks[sidx] = *(const u16x8*)&cqkv[qbase + 256 + col];
    }
  }
  __syncthreads();

  const int w = tid >> 6, l = tid & 63, hi = l >> 4, lo = l & 15;
  f32x4 acc[4] = {};
  #pragma unroll
  for (int kk = 0; kk < 8; ++kk) {
    const int arow = w * 16 + lo;
    s16x8 a = *(const s16x8*)&Qs[arow * 256 + ((hi * 8 + kk * 32) ^ ((arow & 7) << 3))];
    #pragma unroll
    for (int n = 0; n < 4; ++n) {
      const int brow = n * 16 + lo;
      s16x8 bfr = *(const s16x8*)&Ks[brow * 256 + ((hi * 8 + kk * 32) ^ ((brow & 7) << 3))];
      acc[n] = __builtin_amdgcn_mfma_f32_16x16x32_bf16(a, bfr, acc[n], 0, 0, 0);
    }
  }

  // epilogue: add tables, mask, in-register softmax (rows live in 16-lane groups)
  const float scale = 0.0625f;
  int csj[4];
  #pragma unroll
  for (int n = 0; n < 4; ++n) csj[n] = cs[n * 16 + lo];
  float ex[4][4];   // [n][r]
  float wgt[4];     // per r
  #pragma unroll
  for (int r = 0; r < 4; ++r) {
    const int i = w * 16 + hi * 4 + r;
    const long crow = ((long)h * 1024 + cs[i]) * 64;
    const long prow = (long)h * 4096 + (long)i * 64;
    float s[4];
    float mx = -3e38f;
    #pragma unroll
    for (int n = 0; n < 4; ++n) {
      const int j = n * 16 + lo;
      float v = (acc[n][r] + cpqk[crow + j] + pqk[prow + j]) * scale;
      if (csj[n] == 0) v = -1e9f;
      s[n] = v;
      mx = fmaxf(mx, v);
    }
    mx = fmaxf(mx, __shfl_xor(mx, 1));
    mx = fmaxf(mx, __shfl_xor(mx, 2));
    mx = fmaxf(mx, __shfl_xor(mx, 4));
    mx = fmaxf(mx, __shfl_xor(mx, 8));
    float sum = 0.f;
    #pragma unroll
    for (int n = 0; n < 4; ++n) { const float e = __expf(s[n] - mx); ex[n][r] = e; sum += e; }
    sum += __shfl_xor(sum, 1);
    sum += __shfl_xor(sum, 2);
    sum += __shfl_xor(sum, 4);
    sum += __shfl_xor(sum, 8);
    wgt[r] = notm[i] / sum;
  }
  // pooled column partials: sum over rows
  #pragma unroll
  for (int n = 0; n < 4; ++n) {
    float cp = ex[n][0] * wgt[0] + ex[n][1] * wgt[1] + ex[n][2] * wgt[2] + ex[n][3] * wgt[3];
    cp += __shfl_xor(cp, 16);
    cp += __shfl_xor(cp, 32);
    if (hi == 0) poolp[w][n * 16 + lo] = cp;
  }
  __syncthreads();
  if (tid < 64)
    pooled[tid] = (poolp[0][tid] + poolp[1][tid] + poolp[2][tid] + poolp[3][tid]) / nwords;
  __syncthreads();

  // PV: thread owns e = tid
  float o = 0.f;
  const long vbase = hq + 512 + tid;
  #pragma unroll 4
  for (int j = 0; j < 64; ++j) {
    const float vv = b2f(cqkv[(long)cs[j] * 6144 + vbase]) + b2f(pqkv[(long)j * 6144 + vbase]);
    o += pooled[j] * vv;
  }
  outp[(long)b * 2048 + h * 256 + tid] = f2b(o);
}

// ---------------------------------------------------------------------------
// LayerNorm chain (f32), one block per row of 256
// ---------------------------------------------------------------------------
__global__ __launch_bounds__(256) void ln_chain(
    const float* __restrict__ x,
    const float* __restrict__ g1, const float* __restrict__ b1,
    const float* __restrict__ g2, const float* __restrict__ b2,
    const float* __restrict__ g3, const float* __restrict__ b3,
    float* __restrict__ out)
{
  __shared__ float red[4];
  const int b = blockIdx.x, t = threadIdx.x;
  float v = x[(size_t)b * 256 + t];

  auto bsum = [&](float val) -> float {
    #pragma unroll
    for (int o = 32; o; o >>= 1) val += __shfl_down(val, o);
    __syncthreads();
    if ((t & 63) == 0) red[t >> 6] = val;
    __syncthreads();
    return red[0] + red[1] + red[2] + red[3];
  };

  float mean = bsum(v) * (1.f / 256.f);
  float d = v - mean;
  float var = bsum(d * d) * (1.f / 256.f);
  const float y1 = d * rsqrtf(var + 1e-5f) * g1[t] + b1[t];

  mean = bsum(y1) * (1.f / 256.f);
  d = y1 - mean;
  var = bsum(d * d) * (1.f / 256.f);
  const float y2 = d * rsqrtf(var + 1e-6f) * g2[t] + b2[t] + y1;

  mean = bsum(y2) * (1.f / 256.f);
  d = y2 - mean;
  var = bsum(d * d) * (1.f / 256.f);
  out[(size_t)b * 256 + t] = d * rsqrtf(var + 1e-5f) * g3[t] + b3[t];
}

// ---------------------------------------------------------------------------
extern "C" void kernel_launch(void* const* d_in, const int* in_sizes, int n_in,
                              void* d_out, int out_size, void* d_ws, size_t ws_size,
                              hipStream_t stream) {
  (void)in_sizes; (void)n_in; (void)out_size; (void)ws_size;
  const int*   cc    = (const int*)  d_in[0];
  const float* emb_w = (const float*)d_in[1];   // (1024,256)
  const float* qkv_w = (const float*)d_in[2];   // (6144,256)
  const float* fc_w  = (const float*)d_in[3];   // (256,2048)
  const float* fc_b  = (const float*)d_in[4];
  const float* sg    = (const float*)d_in[5];
  const float* sb    = (const float*)d_in[6];
  const float* fg    = (const float*)d_in[7];
  const float* fb    = (const float*)d_in[8];
  const float* bg    = (const float*)d_in[9];
  const float* bbv   = (const float*)d_in[10];
  float* out = (float*)d_out;

  char* p = (char*)d_ws;
  u16* pe_bf   = (u16*)p;  p += (size_t)64 * 256 * 2;
  u16* emb_bf  = (u16*)p;  p += (size_t)1024 * 256 * 2;
  u16* qkvw_bf = (u16*)p;  p += (size_t)6144 * 256 * 2;
  u16* fcw_bf  = (u16*)p;  p += (size_t)256 * 2048 * 2;
  u16* cqkv_bf = (u16*)p;  p += (size_t)1024 * 6144 * 2;
  u16* pqkv_bf = (u16*)p;  p += (size_t)64 * 6144 * 2;
  float* cpqk  = (float*)p; p += (size_t)8 * 1024 * 64 * 4;
  float* pqkf  = (float*)p; p += (size_t)8 * 64 * 64 * 4;
  u16* sdpa_bf = (u16*)p;  p += (size_t)512 * 2048 * 2;
  float* fco   = (float*)p; p += (size_t)512 * 256 * 4;

  // casts + positional encoding
  cast_bf<<<dim3(256),  dim3(256), 0, stream>>>(emb_w, emb_bf,  65536);
  cast_bf<<<dim3(1536), dim3(256), 0, stream>>>(qkv_w, qkvw_bf, 393216);
  cast_bf<<<dim3(512),  dim3(256), 0, stream>>>(fc_w,  fcw_bf,  131072);
  pos_kernel<<<dim3(64), dim3(128), 0, stream>>>(pe_bf);

  // cqkv = emb @ qkv_w^T -> bf16 (1024 x 6144, K=256)
  gemm_bf<true, false, false><<<dim3(96, 16, 1), dim3(256), 0, stream>>>(
      emb_bf, 256, 0, qkvw_bf, 256, 0, cqkv_bf, 6144, 0, nullptr, 256);
  // pqkv = pe @ qkv_w^T -> bf16 (64 x 6144, K=256)
  gemm_bf<true, false, false><<<dim3(96, 1, 1), dim3(256), 0, stream>>>(
      pe_bf, 256, 0, qkvw_bf, 256, 0, pqkv_bf, 6144, 0, nullptr, 256);
  // cpqk[h] = ck_h @ pq_h^T  (1024 x 64, K=256), then += cq_h @ pk_h^T
  gemm_bf<false, false, false><<<dim3(1, 16, 8), dim3(256), 0, stream>>>(
      cqkv_bf + 256, 6144, 768, pqkv_bf, 6144, 768, cpqk, 64, 65536, nullptr, 256);
  gemm_bf<false, true, false><<<dim3(1, 16, 8), dim3(256), 0, stream>>>(
      cqkv_bf, 6144, 768, pqkv_bf + 256, 6144, 768, cpqk, 64, 65536, nullptr, 256);
  // pqk[h] = pq_h @ pk_h^T  (64 x 64, K=256)
  gemm_bf<false, false, false><<<dim3(1, 1, 8), dim3(256), 0, stream>>>(
      pqkv_bf, 6144, 768, pqkv_bf + 256, 6144, 768, pqkf, 64, 4096, nullptr, 256);

  attn_kernel<<<dim3(512, 8), dim3(256), 0, stream>>>(
      cc, cqkv_bf, pqkv_bf, cpqk, pqkf, sdpa_bf);

  // fco = sdpa @ fc_w^T + fc_b  (512 x 256, K=2048), f32 out
  gemm_bf<false, false, true><<<dim3(4, 8, 1), dim3(256), 0, stream>>>(
      sdpa_bf, 2048, 0, fcw_bf, 2048, 0, fco, 256, 0, fc_b, 2048);

  ln_chain<<<dim3(512), dim3(256), 0, stream>>>(fco, sg, sb, fg, fb, bg, bbv, out);
}

// Round 4
// 137.220 us; speedup vs baseline: 3.5450x; 1.4418x over previous
//
#include <hip/hip_runtime.h>
#include <math.h>

typedef unsigned short u16;
typedef __attribute__((ext_vector_type(4))) float f32x4;
typedef __attribute__((ext_vector_type(8))) short s16x8;   // MFMA bf16 frag (8 bf16)
typedef __attribute__((ext_vector_type(4))) unsigned short u16x4;
typedef __attribute__((ext_vector_type(8))) unsigned short u16x8;

__device__ __forceinline__ u16 f2b(float f) {
  union { float f; unsigned u; } v; v.f = f;
  return (u16)((v.u + 0x7fffu + ((v.u >> 16) & 1u)) >> 16);
}
__device__ __forceinline__ float b2f(u16 b) {
  union { unsigned u; float f; } v; v.u = ((unsigned)b) << 16;
  return v.f;
}

// ---------------------------------------------------------------------------
// f32 -> bf16 cast (vectorized, n % 4 == 0)
// ---------------------------------------------------------------------------
__global__ __launch_bounds__(256) void cast_bf(const float* __restrict__ in,
                                               u16* __restrict__ out, int n4) {
  const int i = blockIdx.x * 256 + threadIdx.x;
  if (i < n4) {
    f32x4 v = *(const f32x4*)&in[i * 4];
    u16x4 o = { f2b(v[0]), f2b(v[1]), f2b(v[2]), f2b(v[3]) };
    *(u16x4*)&out[i * 4] = o;
  }
}

// ---------------------------------------------------------------------------
__global__ void pos_kernel(u16* __restrict__ pe) {
  const int m = blockIdx.x;     // 0..63
  const int k = threadIdx.x;    // 0..127
  double f = pow(10000.0, -(double)k / 128.0);
  float ph = (float)m * (float)f;
  pe[m * 256 + 2 * k]     = f2b(sinf(ph));
  pe[m * 256 + 2 * k + 1] = f2b(cosf(ph));
}

// ---------------------------------------------------------------------------
// bf16 MFMA GEMM: C[z][m][n] = sum_k A[z][m][k]*B[z][n][k] (+bias)
// 64x64 tile, 4 waves, BK=64, XOR-swizzled LDS, 16x16x32 MFMA.
// ---------------------------------------------------------------------------
template<bool CBF16, bool BIAS>
__global__ __launch_bounds__(256) void gemm_bf(
    const u16* __restrict__ A, int lda, long sA,
    const u16* __restrict__ B, int ldb, long sB,
    void* __restrict__ Cv, int ldc, long sC,
    const float* __restrict__ bias, int K)
{
  __shared__ __align__(16) u16 As[64 * 64];
  __shared__ __align__(16) u16 Bs[64 * 64];
  const int z = blockIdx.z;
  A += (long)z * sA;  B += (long)z * sB;
  const int m0 = blockIdx.y * 64, n0 = blockIdx.x * 64;
  const int tid = threadIdx.x;
  const int srow = tid >> 2, sq = tid & 3;
  const int w = tid >> 6, l = tid & 63, hi = l >> 4, lo = l & 15;
  f32x4 acc[4] = {};
  for (int k0 = 0; k0 < K; k0 += 64) {
    __syncthreads();
    #pragma unroll
    for (int p = 0; p < 2; ++p) {
      const int col = sq * 16 + p * 8;
      const int sidx = srow * 64 + (col ^ ((srow & 7) << 3));
      *(u16x8*)&As[sidx] = *(const u16x8*)&A[(long)(m0 + srow) * lda + k0 + col];
      *(u16x8*)&Bs[sidx] = *(const u16x8*)&B[(long)(n0 + srow) * ldb + k0 + col];
    }
    __syncthreads();
    #pragma unroll
    for (int kk = 0; kk < 2; ++kk) {
      const int arow = w * 16 + lo;
      s16x8 a = *(const s16x8*)&As[arow * 64 + ((hi * 8 + kk * 32) ^ ((arow & 7) << 3))];
      #pragma unroll
      for (int n = 0; n < 4; ++n) {
        const int brow = n * 16 + lo;
        s16x8 bfr = *(const s16x8*)&Bs[brow * 64 + ((hi * 8 + kk * 32) ^ ((brow & 7) << 3))];
        acc[n] = __builtin_amdgcn_mfma_f32_16x16x32_bf16(a, bfr, acc[n], 0, 0, 0);
      }
    }
  }
  const long zoff = (long)z * sC;
  #pragma unroll
  for (int n = 0; n < 4; ++n) {
    #pragma unroll
    for (int r = 0; r < 4; ++r) {
      const int row = m0 + w * 16 + hi * 4 + r;
      const int col = n0 + n * 16 + lo;
      if (CBF16) {
        ((u16*)Cv)[zoff + (long)row * ldc + col] = f2b(acc[n][r]);
      } else {
        float* C = (float*)Cv;
        float v = acc[n][r];
        if (BIAS)  v += bias[col];
        C[zoff + (long)row * ldc + col] = v;
      }
    }
  }
}

// ---------------------------------------------------------------------------
// cpqk[h][v][j] = ck[v]·pq[j] + cq[v]·pk[j]   (fused dual GEMM)
// M=1024 (grid.y 16), N=64, K=256, batched over h (grid.z 8)
// ---------------------------------------------------------------------------
__global__ __launch_bounds__(256) void gemm_cpqk(
    const u16* __restrict__ cqkv, const u16* __restrict__ pqkv,
    float* __restrict__ C)
{
  __shared__ __align__(16) u16 As1[64 * 64], As2[64 * 64];
  __shared__ __align__(16) u16 Bs1[64 * 64], Bs2[64 * 64];
  const int h = blockIdx.z;
  const long hq = (long)h * 768;
  const int m0 = blockIdx.y * 64;
  const int tid = threadIdx.x;
  const int srow = tid >> 2, sq = tid & 3;
  const int w = tid >> 6, l = tid & 63, hi = l >> 4, lo = l & 15;
  f32x4 acc[4] = {};
  for (int k0 = 0; k0 < 256; k0 += 64) {
    __syncthreads();
    #pragma unroll
    for (int p = 0; p < 2; ++p) {
      const int col = sq * 16 + p * 8;
      const int sidx = srow * 64 + (col ^ ((srow & 7) << 3));
      const long arow = (long)(m0 + srow) * 6144 + hq + k0 + col;
      const long brow = (long)srow * 6144 + hq + k0 + col;
      *(u16x8*)&As1[sidx] = *(const u16x8*)&cqkv[arow + 256];  // ck
      *(u16x8*)&As2[sidx] = *(const u16x8*)&cqkv[arow];        // cq
      *(u16x8*)&Bs1[sidx] = *(const u16x8*)&pqkv[brow];        // pq
      *(u16x8*)&Bs2[sidx] = *(const u16x8*)&pqkv[brow + 256];  // pk
    }
    __syncthreads();
    #pragma unroll
    for (int kk = 0; kk < 2; ++kk) {
      const int arow = w * 16 + lo;
      const int aidx = arow * 64 + ((hi * 8 + kk * 32) ^ ((arow & 7) << 3));
      s16x8 a1 = *(const s16x8*)&As1[aidx];
      s16x8 a2 = *(const s16x8*)&As2[aidx];
      #pragma unroll
      for (int n = 0; n < 4; ++n) {
        const int brow = n * 16 + lo;
        const int bidx = brow * 64 + ((hi * 8 + kk * 32) ^ ((brow & 7) << 3));
        acc[n] = __builtin_amdgcn_mfma_f32_16x16x32_bf16(a1, *(const s16x8*)&Bs1[bidx], acc[n], 0, 0, 0);
        acc[n] = __builtin_amdgcn_mfma_f32_16x16x32_bf16(a2, *(const s16x8*)&Bs2[bidx], acc[n], 0, 0, 0);
      }
    }
  }
  #pragma unroll
  for (int n = 0; n < 4; ++n)
    #pragma unroll
    for (int r = 0; r < 4; ++r)
      C[(long)h * 65536 + (long)(m0 + w * 16 + hi * 4 + r) * 64 + n * 16 + lo] = acc[n][r];
}

// ---------------------------------------------------------------------------
// Attention per (h,b). blockIdx.x = h so XCD k serves head k (L2 affinity).
// sim = (cq[c_i]·ck[c_j] + cpqk[h,c_i,j] + pqk[h,i,j]) / 16 ; mask c_j==0
// Q frags direct global->reg; K in LDS (swizzled); V' reuses K buffer.
// ---------------------------------------------------------------------------
__global__ __launch_bounds__(256) void attn_kernel(
    const int* __restrict__ cc, const u16* __restrict__ cqkv,
    const u16* __restrict__ pqkv, const float* __restrict__ cpqk,
    const float* __restrict__ pqk, u16* __restrict__ outp)
{
  __shared__ __align__(16) u16 Ks[64 * 256];
  __shared__ int   cs[64];
  __shared__ float notm[64];
  __shared__ float poolp[4][64];
  __shared__ float pooled[64];
  __shared__ float nwords;
  const int h = blockIdx.x, b = blockIdx.y;
  const int tid = threadIdx.x;
  const long hq = (long)h * 768;

  if (tid < 64) {
    const int c = cc[b * 64 + tid];
    cs[tid] = c;
    notm[tid] = c ? 1.f : 0.f;
    unsigned long long bm = __ballot(c != 0);
    if (tid == 0) nwords = (float)__popcll(bm);
  }
  __syncthreads();

  const int srow = tid >> 2, sq = tid & 3;
  const int w = tid >> 6, l = tid & 63, hi = l >> 4, lo = l & 15;

  // Q fragments: direct gather global -> registers (16B per kk)
  const long qrow = (long)cs[w * 16 + lo] * 6144 + hq;
  s16x8 a[8];
  #pragma unroll
  for (int kk = 0; kk < 8; ++kk)
    a[kk] = *(const s16x8*)&cqkv[qrow + kk * 32 + hi * 8];

  // stage K (ck rows), XOR-swizzled
  {
    const long kbase = (long)cs[srow] * 6144 + hq + 256;
    #pragma unroll
    for (int p = 0; p < 8; ++p) {
      const int col = sq * 64 + p * 8;
      *(u16x8*)&Ks[srow * 256 + (col ^ ((srow & 7) << 3))] =
          *(const u16x8*)&cqkv[kbase + col];
    }
  }
  __syncthreads();

  f32x4 acc[4] = {};
  #pragma unroll
  for (int kk = 0; kk < 8; ++kk) {
    #pragma unroll
    for (int n = 0; n < 4; ++n) {
      const int brow = n * 16 + lo;
      s16x8 bfr = *(const s16x8*)&Ks[brow * 256 + ((hi * 8 + kk * 32) ^ ((brow & 7) << 3))];
      acc[n] = __builtin_amdgcn_mfma_f32_16x16x32_bf16(a[kk], bfr, acc[n], 0, 0, 0);
    }
  }

  // epilogue: add tables, mask, in-register softmax
  const float scale = 0.0625f;
  int csj[4];
  #pragma unroll
  for (int n = 0; n < 4; ++n) csj[n] = cs[n * 16 + lo];
  float ex[4][4];   // [n][r]
  float wgt[4];
  #pragma unroll
  for (int r = 0; r < 4; ++r) {
    const int i = w * 16 + hi * 4 + r;
    const long crow = ((long)h * 1024 + cs[i]) * 64;
    const long prow = (long)h * 4096 + (long)i * 64;
    float s[4];
    float mx = -3e38f;
    #pragma unroll
    for (int n = 0; n < 4; ++n) {
      const int j = n * 16 + lo;
      float v = (acc[n][r] + cpqk[crow + j] + pqk[prow + j]) * scale;
      if (csj[n] == 0) v = -1e9f;
      s[n] = v;
      mx = fmaxf(mx, v);
    }
    mx = fmaxf(mx, __shfl_xor(mx, 1));
    mx = fmaxf(mx, __shfl_xor(mx, 2));
    mx = fmaxf(mx, __shfl_xor(mx, 4));
    mx = fmaxf(mx, __shfl_xor(mx, 8));
    float sum = 0.f;
    #pragma unroll
    for (int n = 0; n < 4; ++n) { const float e = __expf(s[n] - mx); ex[n][r] = e; sum += e; }
    sum += __shfl_xor(sum, 1);
    sum += __shfl_xor(sum, 2);
    sum += __shfl_xor(sum, 4);
    sum += __shfl_xor(sum, 8);
    wgt[r] = notm[i] / sum;
  }
  #pragma unroll
  for (int n = 0; n < 4; ++n) {
    float cp = ex[n][0] * wgt[0] + ex[n][1] * wgt[1] + ex[n][2] * wgt[2] + ex[n][3] * wgt[3];
    cp += __shfl_xor(cp, 16);
    cp += __shfl_xor(cp, 32);
    if (hi == 0) poolp[w][n * 16 + lo] = cp;
  }
  __syncthreads();   // poolp ready; Ks reads complete

  if (tid < 64)
    pooled[tid] = (poolp[0][tid] + poolp[1][tid] + poolp[2][tid] + poolp[3][tid]) / nwords;

  // stage V' = cv[c_j] + pv[j] into Ks (linear layout, bf16)
  {
    const long vbase = (long)cs[srow] * 6144 + hq + 512;
    const long pbase = (long)srow * 6144 + hq + 512;
    #pragma unroll
    for (int p = 0; p < 8; ++p) {
      const int col = sq * 64 + p * 8;
      u16x8 va = *(const u16x8*)&cqkv[vbase + col];
      u16x8 vb = *(const u16x8*)&pqkv[pbase + col];
      u16x8 o;
      #pragma unroll
      for (int d = 0; d < 8; ++d) o[d] = f2b(b2f(va[d]) + b2f(vb[d]));
      *(u16x8*)&Ks[srow * 256 + col] = o;
    }
  }
  __syncthreads();

  // PV from LDS: thread owns e = tid
  float o = 0.f;
  #pragma unroll
  for (int j = 0; j < 64; ++j)
    o += pooled[j] * b2f(Ks[j * 256 + tid]);
  outp[(long)b * 2048 + h * 256 + tid] = f2b(o);
}

// ---------------------------------------------------------------------------
// LN chain; input = 4 split-K partials of fc output + bias
// ---------------------------------------------------------------------------
__global__ __launch_bounds__(256) void ln_chain(
    const float* __restrict__ xp, const float* __restrict__ fcb,
    const float* __restrict__ g1, const float* __restrict__ b1,
    const float* __restrict__ g2, const float* __restrict__ b2,
    const float* __restrict__ g3, const float* __restrict__ b3,
    float* __restrict__ out)
{
  __shared__ float red[4];
  const int b = blockIdx.x, t = threadIdx.x;
  const long idx = (long)b * 256 + t;
  float v = xp[idx] + xp[idx + 131072] + xp[idx + 262144] + xp[idx + 393216] + fcb[t];

  auto bsum = [&](float val) -> float {
    #pragma unroll
    for (int o = 32; o; o >>= 1) val += __shfl_down(val, o);
    __syncthreads();
    if ((t & 63) == 0) red[t >> 6] = val;
    __syncthreads();
    return red[0] + red[1] + red[2] + red[3];
  };

  float mean = bsum(v) * (1.f / 256.f);
  float d = v - mean;
  float var = bsum(d * d) * (1.f / 256.f);
  const float y1 = d * rsqrtf(var + 1e-5f) * g1[t] + b1[t];

  mean = bsum(y1) * (1.f / 256.f);
  d = y1 - mean;
  var = bsum(d * d) * (1.f / 256.f);
  const float y2 = d * rsqrtf(var + 1e-6f) * g2[t] + b2[t] + y1;

  mean = bsum(y2) * (1.f / 256.f);
  d = y2 - mean;
  var = bsum(d * d) * (1.f / 256.f);
  out[idx] = d * rsqrtf(var + 1e-5f) * g3[t] + b3[t];
}

// ---------------------------------------------------------------------------
extern "C" void kernel_launch(void* const* d_in, const int* in_sizes, int n_in,
                              void* d_out, int out_size, void* d_ws, size_t ws_size,
                              hipStream_t stream) {
  (void)in_sizes; (void)n_in; (void)out_size; (void)ws_size;
  const int*   cc    = (const int*)  d_in[0];
  const float* emb_w = (const float*)d_in[1];   // (1024,256)
  const float* qkv_w = (const float*)d_in[2];   // (6144,256)
  const float* fc_w  = (const float*)d_in[3];   // (256,2048)
  const float* fc_b  = (const float*)d_in[4];
  const float* sg    = (const float*)d_in[5];
  const float* sb    = (const float*)d_in[6];
  const float* fg    = (const float*)d_in[7];
  const float* fb    = (const float*)d_in[8];
  const float* bg    = (const float*)d_in[9];
  const float* bbv   = (const float*)d_in[10];
  float* out = (float*)d_out;

  char* p = (char*)d_ws;
  u16* pe_bf   = (u16*)p;  p += (size_t)64 * 256 * 2;
  u16* emb_bf  = (u16*)p;  p += (size_t)1024 * 256 * 2;
  u16* qkvw_bf = (u16*)p;  p += (size_t)6144 * 256 * 2;
  u16* fcw_bf  = (u16*)p;  p += (size_t)256 * 2048 * 2;
  u16* cqkv_bf = (u16*)p;  p += (size_t)1024 * 6144 * 2;
  u16* pqkv_bf = (u16*)p;  p += (size_t)64 * 6144 * 2;
  float* cpqk  = (float*)p; p += (size_t)8 * 1024 * 64 * 4;
  float* pqkf  = (float*)p; p += (size_t)8 * 64 * 64 * 4;
  u16* sdpa_bf = (u16*)p;  p += (size_t)512 * 2048 * 2;
  float* fco   = (float*)p; p += (size_t)4 * 512 * 256 * 4;

  cast_bf<<<dim3(256),  dim3(256), 0, stream>>>(emb_w, emb_bf,  65536);
  cast_bf<<<dim3(1536), dim3(256), 0, stream>>>(qkv_w, qkvw_bf, 393216);
  cast_bf<<<dim3(512),  dim3(256), 0, stream>>>(fc_w,  fcw_bf,  131072);
  pos_kernel<<<dim3(64), dim3(128), 0, stream>>>(pe_bf);

  // cqkv = emb @ qkv_w^T -> bf16 (1024 x 6144, K=256)
  gemm_bf<true, false><<<dim3(96, 16, 1), dim3(256), 0, stream>>>(
      emb_bf, 256, 0, qkvw_bf, 256, 0, cqkv_bf, 6144, 0, nullptr, 256);
  // pqkv = pe @ qkv_w^T -> bf16 (64 x 6144, K=256)
  gemm_bf<true, false><<<dim3(96, 1, 1), dim3(256), 0, stream>>>(
      pe_bf, 256, 0, qkvw_bf, 256, 0, pqkv_bf, 6144, 0, nullptr, 256);
  // cpqk fused dual GEMM
  gemm_cpqk<<<dim3(1, 16, 8), dim3(256), 0, stream>>>(cqkv_bf, pqkv_bf, cpqk);
  // pqk[h] = pq_h @ pk_h^T  (64 x 64, K=256)
  gemm_bf<false, false><<<dim3(1, 1, 8), dim3(256), 0, stream>>>(
      pqkv_bf, 6144, 768, pqkv_bf + 256, 6144, 768, pqkf, 64, 4096, nullptr, 256);

  // attention: blockIdx.x = h (XCD affinity), y = b
  attn_kernel<<<dim3(8, 512), dim3(256), 0, stream>>>(
      cc, cqkv_bf, pqkv_bf, cpqk, pqkf, sdpa_bf);

  // fc split-K x4: partial[z] = sdpa[:, z*512:+512] @ fc_w[:, z*512:+512]^T
  gemm_bf<false, false><<<dim3(4, 8, 4), dim3(256), 0, stream>>>(
      sdpa_bf, 2048, 512, fcw_bf, 2048, 512, fco, 256, (long)512 * 256, nullptr, 512);

  ln_chain<<<dim3(512), dim3(256), 0, stream>>>(fco, fc_b, sg, sb, fg, fb, bg, bbv, out);
}

// Round 5
// 135.571 us; speedup vs baseline: 3.5881x; 1.0122x over previous
//
#include <hip/hip_runtime.h>
#include <math.h>

typedef unsigned short u16;
typedef __attribute__((ext_vector_type(4))) float f32x4;
typedef __attribute__((ext_vector_type(8))) short s16x8;   // MFMA bf16 frag (8 bf16)
typedef __attribute__((ext_vector_type(4))) unsigned short u16x4;
typedef __attribute__((ext_vector_type(8))) unsigned short u16x8;

__device__ __forceinline__ u16 f2b(float f) {
  union { float f; unsigned u; } v; v.f = f;
  return (u16)((v.u + 0x7fffu + ((v.u >> 16) & 1u)) >> 16);
}
__device__ __forceinline__ float b2f(u16 b) {
  union { unsigned u; float f; } v; v.u = ((unsigned)b) << 16;
  return v.f;
}

// ---------------------------------------------------------------------------
// prep: fused f32->bf16 casts (emb, qkv, fc) + positional encoding
// blocks 0..2303: casts (589824 f32x4 quads); blocks 2304..2335: pos (64x128)
// ---------------------------------------------------------------------------
__global__ __launch_bounds__(256) void prep_kernel(
    const float* __restrict__ emb, const float* __restrict__ qkv,
    const float* __restrict__ fc,
    u16* __restrict__ emb_bf, u16* __restrict__ qkvw_bf, u16* __restrict__ fcw_bf,
    u16* __restrict__ pe)
{
  const int bid = blockIdx.x;
  if (bid < 2304) {
    const int i = bid * 256 + threadIdx.x;
    const float* src; u16* dst; int off;
    if (i < 65536)       { src = emb; dst = emb_bf;  off = i; }
    else if (i < 458752) { src = qkv; dst = qkvw_bf; off = i - 65536; }
    else                 { src = fc;  dst = fcw_bf;  off = i - 458752; }
    f32x4 v = *(const f32x4*)&src[(size_t)off * 4];
    u16x4 o = { f2b(v[0]), f2b(v[1]), f2b(v[2]), f2b(v[3]) };
    *(u16x4*)&dst[(size_t)off * 4] = o;
  } else {
    const int t = threadIdx.x;
    const int m = (bid - 2304) * 2 + (t >> 7);
    const int k = t & 127;
    double f = pow(10000.0, -(double)k / 128.0);
    float ph = (float)m * (float)f;
    pe[m * 256 + 2 * k]     = f2b(sinf(ph));
    pe[m * 256 + 2 * k + 1] = f2b(cosf(ph));
  }
}

// ---------------------------------------------------------------------------
// 128x128-tile bf16 MFMA GEMM (for cqkv): C[m][n] = sum_k A[m][k]*B[n][k]
// 4 waves, each owns a 64x64 quadrant. BK=64. bf16 output.
// ---------------------------------------------------------------------------
__global__ __launch_bounds__(256) void gemm128(
    const u16* __restrict__ A, int lda,
    const u16* __restrict__ B, int ldb,
    u16* __restrict__ C, int ldc, int K)
{
  __shared__ __align__(16) u16 As[128 * 64];
  __shared__ __align__(16) u16 Bs[128 * 64];
  const int m0 = blockIdx.y * 128, n0 = blockIdx.x * 128;
  const int tid = threadIdx.x;
  const int w = tid >> 6, l = tid & 63, hi = l >> 4, lo = l & 15;
  const int wr = (w >> 1) * 64, wc = (w & 1) * 64;
  const int srow = tid >> 3, scol = (tid & 7) * 8;
  f32x4 acc[4][4] = {};
  for (int k0 = 0; k0 < K; k0 += 64) {
    __syncthreads();
    #pragma unroll
    for (int q = 0; q < 4; ++q) {
      const int row = q * 32 + srow;
      const int sidx = row * 64 + (scol ^ ((row & 7) << 3));
      *(u16x8*)&As[sidx] = *(const u16x8*)&A[(long)(m0 + row) * lda + k0 + scol];
      *(u16x8*)&Bs[sidx] = *(const u16x8*)&B[(long)(n0 + row) * ldb + k0 + scol];
    }
    __syncthreads();
    #pragma unroll
    for (int kk = 0; kk < 2; ++kk) {
      s16x8 a[4], bf[4];
      #pragma unroll
      for (int m = 0; m < 4; ++m) {
        const int ar = wr + m * 16 + lo;
        a[m] = *(const s16x8*)&As[ar * 64 + ((hi * 8 + kk * 32) ^ ((ar & 7) << 3))];
      }
      #pragma unroll
      for (int n = 0; n < 4; ++n) {
        const int br = wc + n * 16 + lo;
        bf[n] = *(const s16x8*)&Bs[br * 64 + ((hi * 8 + kk * 32) ^ ((br & 7) << 3))];
      }
      #pragma unroll
      for (int m = 0; m < 4; ++m)
        #pragma unroll
        for (int n = 0; n < 4; ++n)
          acc[m][n] = __builtin_amdgcn_mfma_f32_16x16x32_bf16(a[m], bf[n], acc[m][n], 0, 0, 0);
    }
  }
  #pragma unroll
  for (int m = 0; m < 4; ++m)
    #pragma unroll
    for (int n = 0; n < 4; ++n)
      #pragma unroll
      for (int r = 0; r < 4; ++r)
        C[(long)(m0 + wr + m * 16 + hi * 4 + r) * ldc + n0 + wc + n * 16 + lo] = f2b(acc[m][n][r]);
}

// ---------------------------------------------------------------------------
// 64x64-tile bf16 MFMA GEMM (batched): C[z][m][n] = sum_k A[z][m][k]*B[z][n][k]
// ---------------------------------------------------------------------------
template<bool CBF16, bool BIAS>
__global__ __launch_bounds__(256) void gemm_bf(
    const u16* __restrict__ A, int lda, long sA,
    const u16* __restrict__ B, int ldb, long sB,
    void* __restrict__ Cv, int ldc, long sC,
    const float* __restrict__ bias, int K)
{
  __shared__ __align__(16) u16 As[64 * 64];
  __shared__ __align__(16) u16 Bs[64 * 64];
  const int z = blockIdx.z;
  A += (long)z * sA;  B += (long)z * sB;
  const int m0 = blockIdx.y * 64, n0 = blockIdx.x * 64;
  const int tid = threadIdx.x;
  const int srow = tid >> 2, sq = tid & 3;
  const int w = tid >> 6, l = tid & 63, hi = l >> 4, lo = l & 15;
  f32x4 acc[4] = {};
  for (int k0 = 0; k0 < K; k0 += 64) {
    __syncthreads();
    #pragma unroll
    for (int p = 0; p < 2; ++p) {
      const int col = sq * 16 + p * 8;
      const int sidx = srow * 64 + (col ^ ((srow & 7) << 3));
      *(u16x8*)&As[sidx] = *(const u16x8*)&A[(long)(m0 + srow) * lda + k0 + col];
      *(u16x8*)&Bs[sidx] = *(const u16x8*)&B[(long)(n0 + srow) * ldb + k0 + col];
    }
    __syncthreads();
    #pragma unroll
    for (int kk = 0; kk < 2; ++kk) {
      const int arow = w * 16 + lo;
      s16x8 a = *(const s16x8*)&As[arow * 64 + ((hi * 8 + kk * 32) ^ ((arow & 7) << 3))];
      #pragma unroll
      for (int n = 0; n < 4; ++n) {
        const int brow = n * 16 + lo;
        s16x8 bfr = *(const s16x8*)&Bs[brow * 64 + ((hi * 8 + kk * 32) ^ ((brow & 7) << 3))];
        acc[n] = __builtin_amdgcn_mfma_f32_16x16x32_bf16(a, bfr, acc[n], 0, 0, 0);
      }
    }
  }
  const long zoff = (long)z * sC;
  #pragma unroll
  for (int n = 0; n < 4; ++n) {
    #pragma unroll
    for (int r = 0; r < 4; ++r) {
      const int row = m0 + w * 16 + hi * 4 + r;
      const int col = n0 + n * 16 + lo;
      if (CBF16) {
        ((u16*)Cv)[zoff + (long)row * ldc + col] = f2b(acc[n][r]);
      } else {
        float* C = (float*)Cv;
        float v = acc[n][r];
        if (BIAS)  v += bias[col];
        C[zoff + (long)row * ldc + col] = v;
      }
    }
  }
}

// ---------------------------------------------------------------------------
// cpqk[h][v][j] = ck[v]·pq[j] + cq[v]·pk[j]  (fused dual GEMM, bf16 out)
// ---------------------------------------------------------------------------
__global__ __launch_bounds__(256) void gemm_cpqk(
    const u16* __restrict__ cqkv, const u16* __restrict__ pqkv,
    u16* __restrict__ C)
{
  __shared__ __align__(16) u16 As1[64 * 64], As2[64 * 64];
  __shared__ __align__(16) u16 Bs1[64 * 64], Bs2[64 * 64];
  const int h = blockIdx.z;
  const long hq = (long)h * 768;
  const int m0 = blockIdx.y * 64;
  const int tid = threadIdx.x;
  const int srow = tid >> 2, sq = tid & 3;
  const int w = tid >> 6, l = tid & 63, hi = l >> 4, lo = l & 15;
  f32x4 acc[4] = {};
  for (int k0 = 0; k0 < 256; k0 += 64) {
    __syncthreads();
    #pragma unroll
    for (int p = 0; p < 2; ++p) {
      const int col = sq * 16 + p * 8;
      const int sidx = srow * 64 + (col ^ ((srow & 7) << 3));
      const long arow = (long)(m0 + srow) * 6144 + hq + k0 + col;
      const long brow = (long)srow * 6144 + hq + k0 + col;
      *(u16x8*)&As1[sidx] = *(const u16x8*)&cqkv[arow + 256];  // ck
      *(u16x8*)&As2[sidx] = *(const u16x8*)&cqkv[arow];        // cq
      *(u16x8*)&Bs1[sidx] = *(const u16x8*)&pqkv[brow];        // pq
      *(u16x8*)&Bs2[sidx] = *(const u16x8*)&pqkv[brow + 256];  // pk
    }
    __syncthreads();
    #pragma unroll
    for (int kk = 0; kk < 2; ++kk) {
      const int arow = w * 16 + lo;
      const int aidx = arow * 64 + ((hi * 8 + kk * 32) ^ ((arow & 7) << 3));
      s16x8 a1 = *(const s16x8*)&As1[aidx];
      s16x8 a2 = *(const s16x8*)&As2[aidx];
      #pragma unroll
      for (int n = 0; n < 4; ++n) {
        const int brow = n * 16 + lo;
        const int bidx = brow * 64 + ((hi * 8 + kk * 32) ^ ((brow & 7) << 3));
        acc[n] = __builtin_amdgcn_mfma_f32_16x16x32_bf16(a1, *(const s16x8*)&Bs1[bidx], acc[n], 0, 0, 0);
        acc[n] = __builtin_amdgcn_mfma_f32_16x16x32_bf16(a2, *(const s16x8*)&Bs2[bidx], acc[n], 0, 0, 0);
      }
    }
  }
  #pragma unroll
  for (int n = 0; n < 4; ++n)
    #pragma unroll
    for (int r = 0; r < 4; ++r)
      C[(long)h * 65536 + (long)(m0 + w * 16 + hi * 4 + r) * 64 + n * 16 + lo] = f2b(acc[n][r]);
}

// ---------------------------------------------------------------------------
// Attention per (h,b). blockIdx.x = h -> XCD affinity.
// sim = (cq[c_i]·ck[c_j] + cpqk[h,c_i,j] + pqk[h,i,j]) / 16 ; mask c_j==0
// Q frags global->reg; cv prefetched to regs; K & V' in LDS (both swizzled).
// ---------------------------------------------------------------------------
__global__ __launch_bounds__(256) void attn_kernel(
    const int* __restrict__ cc, const u16* __restrict__ cqkv,
    const u16* __restrict__ pqkv, const u16* __restrict__ cpqk,
    const u16* __restrict__ pqk, u16* __restrict__ outp)
{
  __shared__ __align__(16) u16 Ks[64 * 256];
  __shared__ int   cs[64];
  __shared__ float notm[64];
  __shared__ float poolp[4][64];
  __shared__ float pooled[64];
  __shared__ float nwords;
  const int h = blockIdx.x, b = blockIdx.y;
  const int tid = threadIdx.x;
  const long hq = (long)h * 768;

  if (tid < 64) {
    const int c = cc[b * 64 + tid];
    cs[tid] = c;
    notm[tid] = c ? 1.f : 0.f;
    unsigned long long bm = __ballot(c != 0);
    if (tid == 0) nwords = (float)__popcll(bm);
  }
  __syncthreads();

  const int srow = tid >> 2, sq = tid & 3;
  const int w = tid >> 6, l = tid & 63, hi = l >> 4, lo = l & 15;

  // prefetch cv rows into registers (consumed after softmax)
  const long vrow = (long)cs[srow] * 6144 + hq + 512;
  u16x8 va[8];
  #pragma unroll
  for (int p = 0; p < 8; ++p)
    va[p] = *(const u16x8*)&cqkv[vrow + sq * 64 + p * 8];

  // Q fragments: direct gather global -> registers
  const long qrow = (long)cs[w * 16 + lo] * 6144 + hq;
  s16x8 a[8];
  #pragma unroll
  for (int kk = 0; kk < 8; ++kk)
    a[kk] = *(const s16x8*)&cqkv[qrow + kk * 32 + hi * 8];

  // stage K (ck rows), XOR-swizzled
  {
    const long kbase = (long)cs[srow] * 6144 + hq + 256;
    #pragma unroll
    for (int p = 0; p < 8; ++p) {
      const int col = sq * 64 + p * 8;
      *(u16x8*)&Ks[srow * 256 + (col ^ ((srow & 7) << 3))] =
          *(const u16x8*)&cqkv[kbase + col];
    }
  }
  __syncthreads();

  f32x4 acc[4] = {};
  #pragma unroll
  for (int kk = 0; kk < 8; ++kk) {
    #pragma unroll
    for (int n = 0; n < 4; ++n) {
      const int brow = n * 16 + lo;
      s16x8 bfr = *(const s16x8*)&Ks[brow * 256 + ((hi * 8 + kk * 32) ^ ((brow & 7) << 3))];
      acc[n] = __builtin_amdgcn_mfma_f32_16x16x32_bf16(a[kk], bfr, acc[n], 0, 0, 0);
    }
  }

  // epilogue: add bf16 tables, mask, in-register softmax
  const float scale = 0.0625f;
  int csj[4];
  #pragma unroll
  for (int n = 0; n < 4; ++n) csj[n] = cs[n * 16 + lo];
  float ex[4][4];   // [n][r]
  float wgt[4];
  #pragma unroll
  for (int r = 0; r < 4; ++r) {
    const int i = w * 16 + hi * 4 + r;
    const long crow = ((long)h * 1024 + cs[i]) * 64;
    const long prow = (long)h * 4096 + (long)i * 64;
    float s[4];
    float mx = -3e38f;
    #pragma unroll
    for (int n = 0; n < 4; ++n) {
      const int j = n * 16 + lo;
      float v = (acc[n][r] + b2f(cpqk[crow + j]) + b2f(pqk[prow + j])) * scale;
      if (csj[n] == 0) v = -1e9f;
      s[n] = v;
      mx = fmaxf(mx, v);
    }
    mx = fmaxf(mx, __shfl_xor(mx, 1));
    mx = fmaxf(mx, __shfl_xor(mx, 2));
    mx = fmaxf(mx, __shfl_xor(mx, 4));
    mx = fmaxf(mx, __shfl_xor(mx, 8));
    float sum = 0.f;
    #pragma unroll
    for (int n = 0; n < 4; ++n) { const float e = __expf(s[n] - mx); ex[n][r] = e; sum += e; }
    sum += __shfl_xor(sum, 1);
    sum += __shfl_xor(sum, 2);
    sum += __shfl_xor(sum, 4);
    sum += __shfl_xor(sum, 8);
    wgt[r] = notm[i] / sum;
  }
  #pragma unroll
  for (int n = 0; n < 4; ++n) {
    float cp = ex[n][0] * wgt[0] + ex[n][1] * wgt[1] + ex[n][2] * wgt[2] + ex[n][3] * wgt[3];
    cp += __shfl_xor(cp, 16);
    cp += __shfl_xor(cp, 32);
    if (hi == 0) poolp[w][n * 16 + lo] = cp;
  }
  __syncthreads();   // poolp ready; all K reads complete

  if (tid < 64)
    pooled[tid] = (poolp[0][tid] + poolp[1][tid] + poolp[2][tid] + poolp[3][tid]) / nwords;

  // stage V' = cv(prefetched) + pv into Ks, XOR-swizzled
  {
    const long pbase = (long)srow * 6144 + hq + 512;
    #pragma unroll
    for (int p = 0; p < 8; ++p) {
      const int col = sq * 64 + p * 8;
      u16x8 vb = *(const u16x8*)&pqkv[pbase + col];
      u16x8 o;
      #pragma unroll
      for (int d = 0; d < 8; ++d) o[d] = f2b(b2f(va[p][d]) + b2f(vb[d]));
      *(u16x8*)&Ks[srow * 256 + (col ^ ((srow & 7) << 3))] = o;
    }
  }
  __syncthreads();

  // PV from LDS (swizzle-matched reads): thread owns e = tid
  float o = 0.f;
  #pragma unroll
  for (int j = 0; j < 64; ++j)
    o += pooled[j] * b2f(Ks[j * 256 + (tid ^ ((j & 7) << 3))]);
  outp[(long)b * 2048 + h * 256 + tid] = f2b(o);
}

// ---------------------------------------------------------------------------
// LN chain; input = 4 split-K partials of fc output + bias
// ---------------------------------------------------------------------------
__global__ __launch_bounds__(256) void ln_chain(
    const float* __restrict__ xp, const float* __restrict__ fcb,
    const float* __restrict__ g1, const float* __restrict__ b1,
    const float* __restrict__ g2, const float* __restrict__ b2,
    const float* __restrict__ g3, const float* __restrict__ b3,
    float* __restrict__ out)
{
  __shared__ float red[4];
  const int b = blockIdx.x, t = threadIdx.x;
  const long idx = (long)b * 256 + t;
  float v = xp[idx] + xp[idx + 131072] + xp[idx + 262144] + xp[idx + 393216] + fcb[t];

  auto bsum = [&](float val) -> float {
    #pragma unroll
    for (int o = 32; o; o >>= 1) val += __shfl_down(val, o);
    __syncthreads();
    if ((t & 63) == 0) red[t >> 6] = val;
    __syncthreads();
    return red[0] + red[1] + red[2] + red[3];
  };

  float mean = bsum(v) * (1.f / 256.f);
  float d = v - mean;
  float var = bsum(d * d) * (1.f / 256.f);
  const float y1 = d * rsqrtf(var + 1e-5f) * g1[t] + b1[t];

  mean = bsum(y1) * (1.f / 256.f);
  d = y1 - mean;
  var = bsum(d * d) * (1.f / 256.f);
  const float y2 = d * rsqrtf(var + 1e-6f) * g2[t] + b2[t] + y1;

  mean = bsum(y2) * (1.f / 256.f);
  d = y2 - mean;
  var = bsum(d * d) * (1.f / 256.f);
  out[idx] = d * rsqrtf(var + 1e-5f) * g3[t] + b3[t];
}

// ---------------------------------------------------------------------------
extern "C" void kernel_launch(void* const* d_in, const int* in_sizes, int n_in,
                              void* d_out, int out_size, void* d_ws, size_t ws_size,
                              hipStream_t stream) {
  (void)in_sizes; (void)n_in; (void)out_size; (void)ws_size;
  const int*   cc    = (const int*)  d_in[0];
  const float* emb_w = (const float*)d_in[1];   // (1024,256)
  const float* qkv_w = (const float*)d_in[2];   // (6144,256)
  const float* fc_w  = (const float*)d_in[3];   // (256,2048)
  const float* fc_b  = (const float*)d_in[4];
  const float* sg    = (const float*)d_in[5];
  const float* sb    = (const float*)d_in[6];
  const float* fg    = (const float*)d_in[7];
  const float* fb    = (const float*)d_in[8];
  const float* bg    = (const float*)d_in[9];
  const float* bbv   = (const float*)d_in[10];
  float* out = (float*)d_out;

  char* p = (char*)d_ws;
  u16* pe_bf   = (u16*)p;  p += (size_t)64 * 256 * 2;
  u16* emb_bf  = (u16*)p;  p += (size_t)1024 * 256 * 2;
  u16* qkvw_bf = (u16*)p;  p += (size_t)6144 * 256 * 2;
  u16* fcw_bf  = (u16*)p;  p += (size_t)256 * 2048 * 2;
  u16* cqkv_bf = (u16*)p;  p += (size_t)1024 * 6144 * 2;
  u16* pqkv_bf = (u16*)p;  p += (size_t)64 * 6144 * 2;
  u16* cpqk16  = (u16*)p;  p += (size_t)8 * 1024 * 64 * 2;
  u16* pqk16   = (u16*)p;  p += (size_t)8 * 64 * 64 * 2;
  u16* sdpa_bf = (u16*)p;  p += (size_t)512 * 2048 * 2;
  float* fco   = (float*)p; p += (size_t)4 * 512 * 256 * 4;

  prep_kernel<<<dim3(2336), dim3(256), 0, stream>>>(
      emb_w, qkv_w, fc_w, emb_bf, qkvw_bf, fcw_bf, pe_bf);

  // cqkv = emb @ qkv_w^T -> bf16 (1024 x 6144, K=256), 128x128 tiles
  gemm128<<<dim3(48, 8), dim3(256), 0, stream>>>(
      emb_bf, 256, qkvw_bf, 256, cqkv_bf, 6144, 256);
  // pqkv = pe @ qkv_w^T -> bf16 (64 x 6144, K=256)
  gemm_bf<true, false><<<dim3(96, 1, 1), dim3(256), 0, stream>>>(
      pe_bf, 256, 0, qkvw_bf, 256, 0, pqkv_bf, 6144, 0, nullptr, 256);
  // cpqk fused dual GEMM -> bf16
  gemm_cpqk<<<dim3(1, 16, 8), dim3(256), 0, stream>>>(cqkv_bf, pqkv_bf, cpqk16);
  // pqk[h] = pq_h @ pk_h^T -> bf16 (64 x 64, K=256)
  gemm_bf<true, false><<<dim3(1, 1, 8), dim3(256), 0, stream>>>(
      pqkv_bf, 6144, 768, pqkv_bf + 256, 6144, 768, pqk16, 64, 4096, nullptr, 256);

  // attention: blockIdx.x = h (XCD affinity), y = b
  attn_kernel<<<dim3(8, 512), dim3(256), 0, stream>>>(
      cc, cqkv_bf, pqkv_bf, cpqk16, pqk16, sdpa_bf);

  // fc split-K x4: partial[z] = sdpa[:, z*512:+512] @ fc_w[:, z*512:+512]^T
  gemm_bf<false, false><<<dim3(4, 8, 4), dim3(256), 0, stream>>>(
      sdpa_bf, 2048, 512, fcw_bf, 2048, 512, fco, 256, (long)512 * 256, nullptr, 512);

  ln_chain<<<dim3(512), dim3(256), 0, stream>>>(fco, fc_b, sg, sb, fg, fb, bg, bbv, out);
}

// Round 6
// 96.199 us; speedup vs baseline: 5.0566x; 1.4093x over previous
//
#include <hip/hip_runtime.h>
#include <math.h>

typedef unsigned short u16;
typedef __attribute__((ext_vector_type(4))) float f32x4;
typedef __attribute__((ext_vector_type(8))) short s16x8;   // MFMA bf16 frag (8 bf16)
typedef __attribute__((ext_vector_type(4))) unsigned short u16x4;
typedef __attribute__((ext_vector_type(8))) unsigned short u16x8;

__device__ __forceinline__ u16 f2b(float f) {
  union { float f; unsigned u; } v; v.f = f;
  return (u16)((v.u + 0x7fffu + ((v.u >> 16) & 1u)) >> 16);
}
__device__ __forceinline__ float b2f(u16 b) {
  union { unsigned u; float f; } v; v.u = ((unsigned)b) << 16;
  return v.f;
}

// ---------------------------------------------------------------------------
// prep: fused f32->bf16 casts (emb, qkv, fc->fcx stride 2560) + positional enc
// blocks 0..2303: casts; blocks 2304..2335: pos (64 rows x 128)
// ---------------------------------------------------------------------------
__global__ __launch_bounds__(256) void prep_kernel(
    const float* __restrict__ emb, const float* __restrict__ qkv,
    const float* __restrict__ fc,
    u16* __restrict__ emb_bf, u16* __restrict__ qkvw_bf, u16* __restrict__ fcx,
    u16* __restrict__ pe)
{
  const int bid = blockIdx.x;
  if (bid < 2304) {
    const int i = bid * 256 + threadIdx.x;
    if (i < 65536) {
      f32x4 v = *(const f32x4*)&emb[(size_t)i * 4];
      u16x4 o = { f2b(v[0]), f2b(v[1]), f2b(v[2]), f2b(v[3]) };
      *(u16x4*)&emb_bf[(size_t)i * 4] = o;
    } else if (i < 458752) {
      const int off = i - 65536;
      f32x4 v = *(const f32x4*)&qkv[(size_t)off * 4];
      u16x4 o = { f2b(v[0]), f2b(v[1]), f2b(v[2]), f2b(v[3]) };
      *(u16x4*)&qkvw_bf[(size_t)off * 4] = o;
    } else {
      const int off4 = (i - 458752) * 4;
      const int row = off4 >> 11, col = off4 & 2047;
      f32x4 v = *(const f32x4*)&fc[(size_t)off4];
      u16x4 o = { f2b(v[0]), f2b(v[1]), f2b(v[2]), f2b(v[3]) };
      *(u16x4*)&fcx[(size_t)row * 2560 + col] = o;
    }
  } else {
    const int t = threadIdx.x;
    const int m = (bid - 2304) * 2 + (t >> 7);
    const int k = t & 127;
    double f = pow(10000.0, -(double)k / 128.0);
    float ph = (float)m * (float)f;
    pe[m * 256 + 2 * k]     = f2b(sinf(ph));
    pe[m * 256 + 2 * k + 1] = f2b(cosf(ph));
  }
}

// ---------------------------------------------------------------------------
// 128x128-tile bf16 MFMA GEMM (for cqkv): C[m][n] = sum_k A[m][k]*B[n][k]
// ---------------------------------------------------------------------------
__global__ __launch_bounds__(256) void gemm128(
    const u16* __restrict__ A, int lda,
    const u16* __restrict__ B, int ldb,
    u16* __restrict__ C, int ldc, int K)
{
  __shared__ __align__(16) u16 As[128 * 64];
  __shared__ __align__(16) u16 Bs[128 * 64];
  const int m0 = blockIdx.y * 128, n0 = blockIdx.x * 128;
  const int tid = threadIdx.x;
  const int w = tid >> 6, l = tid & 63, hi = l >> 4, lo = l & 15;
  const int wr = (w >> 1) * 64, wc = (w & 1) * 64;
  const int srow = tid >> 3, scol = (tid & 7) * 8;
  f32x4 acc[4][4] = {};
  for (int k0 = 0; k0 < K; k0 += 64) {
    __syncthreads();
    #pragma unroll
    for (int q = 0; q < 4; ++q) {
      const int row = q * 32 + srow;
      const int sidx = row * 64 + (scol ^ ((row & 7) << 3));
      *(u16x8*)&As[sidx] = *(const u16x8*)&A[(long)(m0 + row) * lda + k0 + scol];
      *(u16x8*)&Bs[sidx] = *(const u16x8*)&B[(long)(n0 + row) * ldb + k0 + scol];
    }
    __syncthreads();
    #pragma unroll
    for (int kk = 0; kk < 2; ++kk) {
      s16x8 a[4], bf[4];
      #pragma unroll
      for (int m = 0; m < 4; ++m) {
        const int ar = wr + m * 16 + lo;
        a[m] = *(const s16x8*)&As[ar * 64 + ((hi * 8 + kk * 32) ^ ((ar & 7) << 3))];
      }
      #pragma unroll
      for (int n = 0; n < 4; ++n) {
        const int br = wc + n * 16 + lo;
        bf[n] = *(const s16x8*)&Bs[br * 64 + ((hi * 8 + kk * 32) ^ ((br & 7) << 3))];
      }
      #pragma unroll
      for (int m = 0; m < 4; ++m)
        #pragma unroll
        for (int n = 0; n < 4; ++n)
          acc[m][n] = __builtin_amdgcn_mfma_f32_16x16x32_bf16(a[m], bf[n], acc[m][n], 0, 0, 0);
    }
  }
  #pragma unroll
  for (int m = 0; m < 4; ++m)
    #pragma unroll
    for (int n = 0; n < 4; ++n)
      #pragma unroll
      for (int r = 0; r < 4; ++r)
        C[(long)(m0 + wr + m * 16 + hi * 4 + r) * ldc + n0 + wc + n * 16 + lo] = f2b(acc[m][n][r]);
}

// ---------------------------------------------------------------------------
// 64x64-tile bf16 MFMA GEMM (batched): C[z][m][n] = sum_k A[z][m][k]*B[z][n][k]
// ---------------------------------------------------------------------------
template<bool CBF16, bool BIAS>
__global__ __launch_bounds__(256) void gemm_bf(
    const u16* __restrict__ A, int lda, long sA,
    const u16* __restrict__ B, int ldb, long sB,
    void* __restrict__ Cv, int ldc, long sC,
    const float* __restrict__ bias, int K)
{
  __shared__ __align__(16) u16 As[64 * 64];
  __shared__ __align__(16) u16 Bs[64 * 64];
  const int z = blockIdx.z;
  A += (long)z * sA;  B += (long)z * sB;
  const int m0 = blockIdx.y * 64, n0 = blockIdx.x * 64;
  const int tid = threadIdx.x;
  const int srow = tid >> 2, sq = tid & 3;
  const int w = tid >> 6, l = tid & 63, hi = l >> 4, lo = l & 15;
  f32x4 acc[4] = {};
  for (int k0 = 0; k0 < K; k0 += 64) {
    __syncthreads();
    #pragma unroll
    for (int p = 0; p < 2; ++p) {
      const int col = sq * 16 + p * 8;
      const int sidx = srow * 64 + (col ^ ((srow & 7) << 3));
      *(u16x8*)&As[sidx] = *(const u16x8*)&A[(long)(m0 + srow) * lda + k0 + col];
      *(u16x8*)&Bs[sidx] = *(const u16x8*)&B[(long)(n0 + srow) * ldb + k0 + col];
    }
    __syncthreads();
    #pragma unroll
    for (int kk = 0; kk < 2; ++kk) {
      const int arow = w * 16 + lo;
      s16x8 a = *(const s16x8*)&As[arow * 64 + ((hi * 8 + kk * 32) ^ ((arow & 7) << 3))];
      #pragma unroll
      for (int n = 0; n < 4; ++n) {
        const int brow = n * 16 + lo;
        s16x8 bfr = *(const s16x8*)&Bs[brow * 64 + ((hi * 8 + kk * 32) ^ ((brow & 7) << 3))];
        acc[n] = __builtin_amdgcn_mfma_f32_16x16x32_bf16(a, bfr, acc[n], 0, 0, 0);
      }
    }
  }
  const long zoff = (long)z * sC;
  #pragma unroll
  for (int n = 0; n < 4; ++n) {
    #pragma unroll
    for (int r = 0; r < 4; ++r) {
      const int row = m0 + w * 16 + hi * 4 + r;
      const int col = n0 + n * 16 + lo;
      if (CBF16) {
        ((u16*)Cv)[zoff + (long)row * ldc + col] = f2b(acc[n][r]);
      } else {
        float* C = (float*)Cv;
        float v = acc[n][r];
        if (BIAS)  v += bias[col];
        C[zoff + (long)row * ldc + col] = v;
      }
    }
  }
}

// ---------------------------------------------------------------------------
// cpqk[h][v][j] = ck[v]·pq[j] + cq[v]·pk[j]  (fused dual GEMM, bf16 out)
// ---------------------------------------------------------------------------
__global__ __launch_bounds__(256) void gemm_cpqk(
    const u16* __restrict__ cqkv, const u16* __restrict__ pqkv,
    u16* __restrict__ C)
{
  __shared__ __align__(16) u16 As1[64 * 64], As2[64 * 64];
  __shared__ __align__(16) u16 Bs1[64 * 64], Bs2[64 * 64];
  const int h = blockIdx.z;
  const long hq = (long)h * 768;
  const int m0 = blockIdx.y * 64;
  const int tid = threadIdx.x;
  const int srow = tid >> 2, sq = tid & 3;
  const int w = tid >> 6, l = tid & 63, hi = l >> 4, lo = l & 15;
  f32x4 acc[4] = {};
  for (int k0 = 0; k0 < 256; k0 += 64) {
    __syncthreads();
    #pragma unroll
    for (int p = 0; p < 2; ++p) {
      const int col = sq * 16 + p * 8;
      const int sidx = srow * 64 + (col ^ ((srow & 7) << 3));
      const long arow = (long)(m0 + srow) * 6144 + hq + k0 + col;
      const long brow = (long)srow * 6144 + hq + k0 + col;
      *(u16x8*)&As1[sidx] = *(const u16x8*)&cqkv[arow + 256];  // ck
      *(u16x8*)&As2[sidx] = *(const u16x8*)&cqkv[arow];        // cq
      *(u16x8*)&Bs1[sidx] = *(const u16x8*)&pqkv[brow];        // pq
      *(u16x8*)&Bs2[sidx] = *(const u16x8*)&pqkv[brow + 256];  // pk
    }
    __syncthreads();
    #pragma unroll
    for (int kk = 0; kk < 2; ++kk) {
      const int arow = w * 16 + lo;
      const int aidx = arow * 64 + ((hi * 8 + kk * 32) ^ ((arow & 7) << 3));
      s16x8 a1 = *(const s16x8*)&As1[aidx];
      s16x8 a2 = *(const s16x8*)&As2[aidx];
      #pragma unroll
      for (int n = 0; n < 4; ++n) {
        const int brow = n * 16 + lo;
        const int bidx = brow * 64 + ((hi * 8 + kk * 32) ^ ((brow & 7) << 3));
        acc[n] = __builtin_amdgcn_mfma_f32_16x16x32_bf16(a1, *(const s16x8*)&Bs1[bidx], acc[n], 0, 0, 0);
        acc[n] = __builtin_amdgcn_mfma_f32_16x16x32_bf16(a2, *(const s16x8*)&Bs2[bidx], acc[n], 0, 0, 0);
      }
    }
  }
  #pragma unroll
  for (int n = 0; n < 4; ++n)
    #pragma unroll
    for (int r = 0; r < 4; ++r)
      C[(long)h * 65536 + (long)(m0 + w * 16 + hi * 4 + r) * 64 + n * 16 + lo] = f2b(acc[n][r]);
}

// ---------------------------------------------------------------------------
// Attention per (h,b). blockIdx.x = h -> XCD affinity.
// sim = (cq[c_i]·ck[c_j] + cpqk[h,c_i,j] + pqk[h,i,j]) / 16 ; mask c_j==0
// All gathers line-coalesced; tables staged via LDS (dead K region);
// pv-term removed (folded into fc GEMM); writes attn-out + pooled.
// ---------------------------------------------------------------------------
__global__ __launch_bounds__(256, 4) void attn_kernel(
    const int* __restrict__ cc, const u16* __restrict__ cqkv,
    const u16* __restrict__ cpqk, const u16* __restrict__ pqk,
    u16* __restrict__ outp)
{
  __shared__ __align__(16) u16 Ks[64 * 256];
  __shared__ int   cs[64];
  __shared__ float notm[64];
  __shared__ float poolp[4][64];
  __shared__ float pooled[64];
  __shared__ float nwords;
  const int h = blockIdx.x, b = blockIdx.y;
  const int tid = threadIdx.x;
  const long hq = (long)h * 768;

  if (tid < 64) {
    const int c = cc[b * 64 + tid];
    cs[tid] = c;
    notm[tid] = c ? 1.f : 0.f;
    unsigned long long bm = __ballot(c != 0);
    if (tid == 0) nwords = (float)__popcll(bm);
  }
  __syncthreads();

  const int srow = tid >> 2, sq = tid & 3;
  const int w = tid >> 6, l = tid & 63, hi = l >> 4, lo = l & 15;
  const int swz = (srow & 7) << 3;
  const int ci_s = cs[srow];

  // table rows (by i=srow; cpqk gathered via c_i) -> regs, line-coalesced
  const long crow = ((long)h * 1024 + ci_s) * 64;
  const long prow = (long)h * 4096 + (long)srow * 64;
  u16x8 ct0 = *(const u16x8*)&cpqk[crow + sq * 8];
  u16x8 ct1 = *(const u16x8*)&cpqk[crow + sq * 8 + 32];
  u16x8 pt0 = *(const u16x8*)&pqk[prow + sq * 8];
  u16x8 pt1 = *(const u16x8*)&pqk[prow + sq * 8 + 32];

  // Q fragments: direct gather global -> registers (line-coalesced across hi)
  const long qrow = (long)cs[w * 16 + lo] * 6144 + hq;
  s16x8 a[8];
  #pragma unroll
  for (int kk = 0; kk < 8; ++kk)
    a[kk] = *(const s16x8*)&cqkv[qrow + kk * 32 + hi * 8];

  // K rows -> regs -> LDS (XOR-swizzled), line-coalesced loads
  {
    const long kbase = (long)ci_s * 6144 + hq + 256;
    u16x8 kr[8];
    #pragma unroll
    for (int p = 0; p < 8; ++p)
      kr[p] = *(const u16x8*)&cqkv[kbase + sq * 8 + p * 32];
    #pragma unroll
    for (int p = 0; p < 8; ++p)
      *(u16x8*)&Ks[srow * 256 + ((sq * 8 + p * 32) ^ swz)] = kr[p];
  }

  // cv prefetch (consumed at V' stage), line-coalesced
  const long vrow = (long)ci_s * 6144 + hq + 512;
  u16x8 va[8];
  #pragma unroll
  for (int p = 0; p < 8; ++p)
    va[p] = *(const u16x8*)&cqkv[vrow + sq * 8 + p * 32];

  __syncthreads();

  f32x4 acc[4] = {};
  #pragma unroll
  for (int kk = 0; kk < 8; ++kk) {
    #pragma unroll
    for (int n = 0; n < 4; ++n) {
      const int brow = n * 16 + lo;
      s16x8 bfr = *(const s16x8*)&Ks[brow * 256 + ((hi * 8 + kk * 32) ^ ((brow & 7) << 3))];
      acc[n] = __builtin_amdgcn_mfma_f32_16x16x32_bf16(a[kk], bfr, acc[n], 0, 0, 0);
    }
  }
  __syncthreads();   // K data in Ks now dead

  // stage tables into Ks[0:8192]: cpqk_s = [0,4096), pqk_s = [4096,8192)
  *(u16x8*)&Ks[srow * 64 + ((sq * 8) ^ swz)]          = ct0;
  *(u16x8*)&Ks[srow * 64 + ((sq * 8 + 32) ^ swz)]     = ct1;
  *(u16x8*)&Ks[4096 + srow * 64 + ((sq * 8) ^ swz)]      = pt0;
  *(u16x8*)&Ks[4096 + srow * 64 + ((sq * 8 + 32) ^ swz)] = pt1;
  __syncthreads();

  // epilogue: add tables (LDS), mask, in-register softmax
  const float scale = 0.0625f;
  int csj[4];
  #pragma unroll
  for (int n = 0; n < 4; ++n) csj[n] = cs[n * 16 + lo];
  float ex[4][4];   // [n][r]
  float wgt[4];
  #pragma unroll
  for (int r = 0; r < 4; ++r) {
    const int i = w * 16 + hi * 4 + r;
    const int tswz = (i & 7) << 3;
    float s[4];
    float mx = -3e38f;
    #pragma unroll
    for (int n = 0; n < 4; ++n) {
      const int j = n * 16 + lo;
      const int cidx = i * 64 + (j ^ tswz);
      float v = (acc[n][r] + b2f(Ks[cidx]) + b2f(Ks[4096 + cidx])) * scale;
      if (csj[n] == 0) v = -1e9f;
      s[n] = v;
      mx = fmaxf(mx, v);
    }
    mx = fmaxf(mx, __shfl_xor(mx, 1));
    mx = fmaxf(mx, __shfl_xor(mx, 2));
    mx = fmaxf(mx, __shfl_xor(mx, 4));
    mx = fmaxf(mx, __shfl_xor(mx, 8));
    float sum = 0.f;
    #pragma unroll
    for (int n = 0; n < 4; ++n) { const float e = __expf(s[n] - mx); ex[n][r] = e; sum += e; }
    sum += __shfl_xor(sum, 1);
    sum += __shfl_xor(sum, 2);
    sum += __shfl_xor(sum, 4);
    sum += __shfl_xor(sum, 8);
    wgt[r] = notm[i] / sum;
  }
  #pragma unroll
  for (int n = 0; n < 4; ++n) {
    float cp = ex[n][0] * wgt[0] + ex[n][1] * wgt[1] + ex[n][2] * wgt[2] + ex[n][3] * wgt[3];
    cp += __shfl_xor(cp, 16);
    cp += __shfl_xor(cp, 32);
    if (hi == 0) poolp[w][n * 16 + lo] = cp;
  }
  __syncthreads();   // poolp ready; table reads complete

  float pval = 0.f;
  if (tid < 64) {
    pval = (poolp[0][tid] + poolp[1][tid] + poolp[2][tid] + poolp[3][tid]) / nwords;
    pooled[tid] = pval;
  }

  // stage cv (prefetched regs) into Ks, XOR-swizzled
  #pragma unroll
  for (int p = 0; p < 8; ++p)
    *(u16x8*)&Ks[srow * 256 + ((sq * 8 + p * 32) ^ swz)] = va[p];

  if (tid < 64)
    outp[(long)b * 2560 + 2048 + h * 64 + tid] = f2b(pval);
  __syncthreads();

  // PV (cv-term only): thread owns e = tid
  float o = 0.f;
  #pragma unroll
  for (int j = 0; j < 64; ++j)
    o += pooled[j] * b2f(Ks[j * 256 + (tid ^ ((j & 7) << 3))]);
  outp[(long)b * 2560 + h * 256 + tid] = f2b(o);
}

// ---------------------------------------------------------------------------
// LN chain; input = 4 split-K partials of fc output + bias
// ---------------------------------------------------------------------------
__global__ __launch_bounds__(256) void ln_chain(
    const float* __restrict__ xp, const float* __restrict__ fcb,
    const float* __restrict__ g1, const float* __restrict__ b1,
    const float* __restrict__ g2, const float* __restrict__ b2,
    const float* __restrict__ g3, const float* __restrict__ b3,
    float* __restrict__ out)
{
  __shared__ float red[4];
  const int b = blockIdx.x, t = threadIdx.x;
  const long idx = (long)b * 256 + t;
  float v = xp[idx] + xp[idx + 131072] + xp[idx + 262144] + xp[idx + 393216] + fcb[t];

  auto bsum = [&](float val) -> float {
    #pragma unroll
    for (int o = 32; o; o >>= 1) val += __shfl_down(val, o);
    __syncthreads();
    if ((t & 63) == 0) red[t >> 6] = val;
    __syncthreads();
    return red[0] + red[1] + red[2] + red[3];
  };

  float mean = bsum(v) * (1.f / 256.f);
  float d = v - mean;
  float var = bsum(d * d) * (1.f / 256.f);
  const float y1 = d * rsqrtf(var + 1e-5f) * g1[t] + b1[t];

  mean = bsum(y1) * (1.f / 256.f);
  d = y1 - mean;
  var = bsum(d * d) * (1.f / 256.f);
  const float y2 = d * rsqrtf(var + 1e-6f) * g2[t] + b2[t] + y1;

  mean = bsum(y2) * (1.f / 256.f);
  d = y2 - mean;
  var = bsum(d * d) * (1.f / 256.f);
  out[idx] = d * rsqrtf(var + 1e-5f) * g3[t] + b3[t];
}

// ---------------------------------------------------------------------------
extern "C" void kernel_launch(void* const* d_in, const int* in_sizes, int n_in,
                              void* d_out, int out_size, void* d_ws, size_t ws_size,
                              hipStream_t stream) {
  (void)in_sizes; (void)n_in; (void)out_size; (void)ws_size;
  const int*   cc    = (const int*)  d_in[0];
  const float* emb_w = (const float*)d_in[1];   // (1024,256)
  const float* qkv_w = (const float*)d_in[2];   // (6144,256)
  const float* fc_w  = (const float*)d_in[3];   // (256,2048)
  const float* fc_b  = (const float*)d_in[4];
  const float* sg    = (const float*)d_in[5];
  const float* sb    = (const float*)d_in[6];
  const float* fg    = (const float*)d_in[7];
  const float* fb    = (const float*)d_in[8];
  const float* bg    = (const float*)d_in[9];
  const float* bbv   = (const float*)d_in[10];
  float* out = (float*)d_out;

  char* p = (char*)d_ws;
  u16* pe_bf   = (u16*)p;  p += (size_t)64 * 256 * 2;
  u16* emb_bf  = (u16*)p;  p += (size_t)1024 * 256 * 2;
  u16* qkvw_bf = (u16*)p;  p += (size_t)6144 * 256 * 2;
  u16* fcx     = (u16*)p;  p += (size_t)256 * 2560 * 2;    // [fc_w | pvfc]
  u16* cqkv_bf = (u16*)p;  p += (size_t)1024 * 6144 * 2;
  u16* pqkv_bf = (u16*)p;  p += (size_t)64 * 6144 * 2;
  u16* cpqk16  = (u16*)p;  p += (size_t)8 * 1024 * 64 * 2;
  u16* pqk16   = (u16*)p;  p += (size_t)8 * 64 * 64 * 2;
  u16* sdpa_bf = (u16*)p;  p += (size_t)512 * 2560 * 2;    // [attn-out | pooled]
  float* fco   = (float*)p; p += (size_t)4 * 512 * 256 * 4;

  prep_kernel<<<dim3(2336), dim3(256), 0, stream>>>(
      emb_w, qkv_w, fc_w, emb_bf, qkvw_bf, fcx, pe_bf);

  // cqkv = emb @ qkv_w^T -> bf16 (1024 x 6144, K=256), 128x128 tiles
  gemm128<<<dim3(48, 8), dim3(256), 0, stream>>>(
      emb_bf, 256, qkvw_bf, 256, cqkv_bf, 6144, 256);
  // pqkv = pe @ qkv_w^T -> bf16 (64 x 6144, K=256)
  gemm_bf<true, false><<<dim3(96, 1, 1), dim3(256), 0, stream>>>(
      pe_bf, 256, 0, qkvw_bf, 256, 0, pqkv_bf, 6144, 0, nullptr, 256);
  // cpqk fused dual GEMM -> bf16
  gemm_cpqk<<<dim3(1, 16, 8), dim3(256), 0, stream>>>(cqkv_bf, pqkv_bf, cpqk16);
  // pqk[h] = pq_h @ pk_h^T -> bf16 (64 x 64, K=256)
  gemm_bf<true, false><<<dim3(1, 1, 8), dim3(256), 0, stream>>>(
      pqkv_bf, 6144, 768, pqkv_bf + 256, 6144, 768, pqk16, 64, 4096, nullptr, 256);
  // pvfc[h]: fcx[n][2048 + h*64 + j] = sum_e fc_w[n][h*256+e] * pv[j][h-slice e]
  gemm_bf<true, false><<<dim3(1, 4, 8), dim3(256), 0, stream>>>(
      fcx, 2560, 256, pqkv_bf + 512, 6144, 768, fcx + 2048, 2560, 64, nullptr, 256);

  // attention: blockIdx.x = h (XCD affinity), y = b
  attn_kernel<<<dim3(8, 512), dim3(256), 0, stream>>>(
      cc, cqkv_bf, cpqk16, pqk16, sdpa_bf);

  // fc split-K x4 over K=2560: partial[z] = A'[:, z*640:+640] @ B'[:, z*640:+640]^T
  gemm_bf<false, false><<<dim3(4, 8, 4), dim3(256), 0, stream>>>(
      sdpa_bf, 2560, 640, fcx, 2560, 640, fco, 256, (long)512 * 256, nullptr, 640);

  ln_chain<<<dim3(512), dim3(256), 0, stream>>>(fco, fc_b, sg, sb, fg, fb, bg, bbv, out);
}